// Round 13
// baseline (134.502 us; speedup 1.0000x reference)
//
#include <hip/hip_runtime.h>
#include <math.h>

#define NB   16
#define NS   2048
#define ND   128
#define NH   4
#define NHD  32
#define NROWS (NB * NS)   // 32768

typedef unsigned short u16;
typedef __bf16 bf16x8 __attribute__((ext_vector_type(8)));
typedef float  f32x4  __attribute__((ext_vector_type(4)));
typedef float  f32x16 __attribute__((ext_vector_type(16)));

static __device__ __forceinline__ u16 f2bf(float a) {
    union { __bf16 h; u16 u; } t; t.h = (__bf16)a; return t.u;
}
static __device__ __forceinline__ unsigned int pk2(float a, float b) {
    union { __bf16 h[2]; unsigned int u; } t;
    t.h[0] = (__bf16)a; t.h[1] = (__bf16)b; return t.u;
}

#if __has_builtin(__builtin_amdgcn_exp2f)
#define EXP2(x) __builtin_amdgcn_exp2f(x)
#else
extern "C" __device__ float __ocml_native_exp2_f32(float);
#define EXP2(x) __ocml_native_exp2_f32(x)
#endif

// q pre-scale: 1/sqrt(32) * log2(e)  -> softmax via raw v_exp_f32
#define QSCALE (0.17677669529663687f * 1.4426950408889634f)

// ============================================================
// Kernel 0: prep — 6 weights fp32 [k][n] -> bf16 transposed Wt[n][k].
// ============================================================
__global__ __launch_bounds__(256) void prep_kernel(
    const float* __restrict__ Wq, const float* __restrict__ Wk,
    const float* __restrict__ Wv, const float* __restrict__ Wo,
    const float* __restrict__ W1, const float* __restrict__ W2,
    u16* __restrict__ wt)
{
    const int wb = blockIdx.x, tid = threadIdx.x;   // wb 0..47
    const int widx = wb >> 3, sub = wb & 7;
    const float* W = widx == 0 ? Wq : widx == 1 ? Wk : widx == 2 ? Wv
                   : widx == 3 ? Wo : widx == 4 ? W1 : W2;
    const int flat8 = sub * 256 + tid;    // 0..2047
    const int n = flat8 >> 4, k0 = (flat8 & 15) * 8;
    float v[8];
    #pragma unroll
    for (int j = 0; j < 8; ++j) v[j] = W[(size_t)(k0 + j) * ND + n];
    int4 o;
    o.x = pk2(v[0], v[1]); o.y = pk2(v[2], v[3]);
    o.z = pk2(v[4], v[5]); o.w = pk2(v[6], v[7]);
    *reinterpret_cast<int4*>(wt + (size_t)widx * 16384 + (size_t)n * ND + k0) = o;
}

// ============================================================
// Kernel 1: fused QKV, zero-LDS, HIGH-TLP: 16 rows/block, 4 col-split
// waves (wave cw = 16 rows x 32 cols, nb=2). Grid 2048 -> 8 blocks/CU.
// Q,K use swapped-operand MFMA (C = [out_dim][spos], direct uint2 stores);
// V normal order (C = [spos][out_dim], frag-packed uint2).
// ============================================================
__global__ __launch_bounds__(256) void qkv_mfma_kernel(
    const float* __restrict__ x,
    const u16* __restrict__ wtq, const u16* __restrict__ wtk, const u16* __restrict__ wtv,
    const float* __restrict__ bq, const float* __restrict__ bk, const float* __restrict__ bv,
    u16* __restrict__ qo, u16* __restrict__ kvf)
{
    const int tid = threadIdx.x, lane = tid & 63, cw = tid >> 6;  // cw 0..3
    const int n = lane & 15, c = lane >> 4;
    const int row0 = blockIdx.x * 16;

    bf16x8 a[4];
    #pragma unroll
    for (int kk = 0; kk < 4; ++kk) {
        const float* xp = x + (size_t)(row0 + n) * ND + kk * 32 + c * 8;
        float4 f0 = *reinterpret_cast<const float4*>(xp);
        float4 f1 = *reinterpret_cast<const float4*>(xp + 4);
        union { unsigned int u[4]; bf16x8 v; } t;
        t.u[0] = pk2(f0.x, f0.y); t.u[1] = pk2(f0.z, f0.w);
        t.u[2] = pk2(f1.x, f1.y); t.u[3] = pk2(f1.z, f1.w);
        a[kk] = t.v;
    }

    f32x4 accq[2], acck[2], accv[2];
    #pragma unroll
    for (int nb = 0; nb < 2; ++nb) {
        accq[nb] = f32x4{0.f, 0.f, 0.f, 0.f};
        acck[nb] = f32x4{0.f, 0.f, 0.f, 0.f};
        accv[nb] = f32x4{0.f, 0.f, 0.f, 0.f};
    }

    #pragma unroll
    for (int kk = 0; kk < 4; ++kk) {
        #pragma unroll
        for (int nb = 0; nb < 2; ++nb) {
            const size_t boff = (size_t)(cw * 32 + nb * 16 + n) * ND + kk * 32 + c * 8;
            bf16x8 bqf = *reinterpret_cast<const bf16x8*>(wtq + boff);
            bf16x8 bkf = *reinterpret_cast<const bf16x8*>(wtk + boff);
            bf16x8 bvf = *reinterpret_cast<const bf16x8*>(wtv + boff);
            // swapped: C = [out_dim][spos]
            accq[nb] = __builtin_amdgcn_mfma_f32_16x16x32_bf16(bqf, a[kk], accq[nb], 0, 0, 0);
            acck[nb] = __builtin_amdgcn_mfma_f32_16x16x32_bf16(bkf, a[kk], acck[nb], 0, 0, 0);
            // normal: C = [spos][out_dim]
            accv[nb] = __builtin_amdgcn_mfma_f32_16x16x32_bf16(a[kk], bvf, accv[nb], 0, 0, 0);
        }
    }

    const int b    = row0 >> 11;
    const int sp0  = row0 & (NS - 1);              // 16-aligned
    const int spos = sp0 + n;                      // Q/K row owned by this lane
    const int T = spos >> 5, l5 = spos & 31;

    #pragma unroll
    for (int nb = 0; nb < 2; ++nb) {
        // ---- Q, K (swapped layout): dims d0..d0+3 of row `spos` ----
        const int d0  = cw * 32 + nb * 16 + 4 * c;
        const int hh  = d0 >> 5, d32 = d0 & 31;
        const size_t kvb  = ((size_t)b * NH + hh) * (NS * NHD);
        const size_t kvb2 = ((size_t)b * NH + hh) * (2 * NS * NHD);
        const float4 bq4 = *reinterpret_cast<const float4*>(bq + d0);
        const float4 bk4 = *reinterpret_cast<const float4*>(bk + d0);
        float q0 = (accq[nb][0] + bq4.x) * QSCALE;
        float q1 = (accq[nb][1] + bq4.y) * QSCALE;
        float q2 = (accq[nb][2] + bq4.z) * QSCALE;
        float q3 = (accq[nb][3] + bq4.w) * QSCALE;
        *reinterpret_cast<uint2*>(qo + kvb + (size_t)spos * NHD + d32) =
            make_uint2(pk2(q0, q1), pk2(q2, q3));
        float k0 = acck[nb][0] + bk4.x, k1 = acck[nb][1] + bk4.y;
        float k2 = acck[nb][2] + bk4.z, k3 = acck[nb][3] + bk4.w;
        const int s2 = d32 >> 4, c2 = (d32 >> 3) & 1, j0 = d32 & 7;  // j0 in {0,4}
        *reinterpret_cast<uint2*>(
            kvf + kvb2 + (size_t)T * 2048 + s2 * 512 + (size_t)(l5 + 32 * c2) * 8 + j0) =
            make_uint2(pk2(k0, k1), pk2(k2, k3));

        // ---- V (normal layout): keys sp0+4c..+3, dim dcol ----
        const int dcol = cw * 32 + nb * 16 + n;
        const int hhv = dcol >> 5, dv32 = dcol & 31;
        const size_t kvb2v = ((size_t)b * NH + hhv) * (2 * NS * NHD);
        const float bvv = bv[dcol];
        const int u2 = sp0 >> 4;
        const int lanep = dv32 + 32 * (c & 1);
        const int jv0 = 4 * (c >> 1);
        float v0 = accv[nb][0] + bvv, v1 = accv[nb][1] + bvv;
        float v2 = accv[nb][2] + bvv, v3 = accv[nb][3] + bvv;
        *reinterpret_cast<uint2*>(
            kvf + kvb2v + (size_t)(u2 >> 1) * 2048 + 1024 + (u2 & 1) * 512
                + (size_t)lanep * 8 + jv0) =
            make_uint2(pk2(v0, v1), pk2(v2, v3));
    }
}

// ============================================================
// Kernel 2: MFMA flash attention — FROZEN at R12 (67.6us):
// R6 structure + dn via ones-MFMA + interleaved K|V stream.
// ============================================================
__global__ __launch_bounds__(256) void attn_mfma_kernel(
    const u16* __restrict__ qg,   // (B,H,S,32) row-major bf16, pre-scaled
    const u16* __restrict__ kvf,  // interleaved frag-packed K|V
    u16* __restrict__ ao)         // (B,S,128) bf16
{
    __shared__ float Ol[2][64][17];
    __shared__ float Dl[2][64];

    const int tid = threadIdx.x, lane = tid & 63, w = tid >> 6;
    const int qhalf = w >> 1, khalf = w & 1;

    // XCD swizzle: bid = qblk*64 + g*8 + xcd  ->  bh = xcd*8 + g
    const int bid  = blockIdx.x;
    const int bh   = (bid & 7) * 8 + ((bid >> 3) & 7);
    const int qblk = bid >> 6;                 // 0..31
    const int b = bh >> 2, h = bh & 3;
    const int n = lane & 31, hf = lane >> 5;
    const int q0w = qblk * 64 + qhalf * 32;

    const size_t qbase = (size_t)bh * (NS * NHD);
    const bf16x8 qf0 = *reinterpret_cast<const bf16x8*>(
        qg + qbase + (size_t)(q0w + n) * NHD + 8 * hf);
    const bf16x8 qf1 = *reinterpret_cast<const bf16x8*>(
        qg + qbase + (size_t)(q0w + n) * NHD + 16 + 8 * hf);

    union { unsigned int u[4]; bf16x8 v; } ONES;
    ONES.u[0] = 0x3F803F80u; ONES.u[1] = 0x3F803F80u;
    ONES.u[2] = 0x3F803F80u; ONES.u[3] = 0x3F803F80u;

    f32x16 ot, dn, zz;
    #pragma unroll
    for (int i = 0; i < 16; ++i) { ot[i] = 0.f; dn[i] = 0.f; zz[i] = 0.f; }

    // wave's key half: 32 interleaved 4KB chunks (K at +0/+512, V at +1024/+1536)
    const u16* kv = kvf + (size_t)bh * (2 * NS * NHD) + (size_t)lane * 8
                        + (size_t)khalf * 32 * 2048;

    auto LDK = [&](int t, int half) {
        return *reinterpret_cast<const bf16x8*>(kv + (size_t)t * 2048 + half * 512);
    };
    auto LDV = [&](int t, int half) {
        return *reinterpret_cast<const bf16x8*>(kv + (size_t)t * 2048 + 1024 + half * 512);
    };
    auto EXPPACK = [&](const f32x16& s, bf16x8& w0, bf16x8& w1) {
        union { unsigned int u[4]; bf16x8 v; } a0, a1;
        #pragma unroll
        for (int i = 0; i < 4; ++i)
            a0.u[i] = pk2(EXP2(s[2 * i]), EXP2(s[2 * i + 1]));
        #pragma unroll
        for (int i = 0; i < 4; ++i)
            a1.u[i] = pk2(EXP2(s[8 + 2 * i]), EXP2(s[9 + 2 * i]));
        w0 = a0.v; w1 = a1.v;
    };

    // ---- prologue: tile 0 ----
    bf16x8 kA0 = LDK(0, 0), kA1 = LDK(0, 1);
    bf16x8 vA0 = LDV(0, 0), vA1 = LDV(0, 1);
    f32x16 s;
    s = __builtin_amdgcn_mfma_f32_32x32x16_bf16(kA0, qf0, zz, 0, 0, 0);
    s = __builtin_amdgcn_mfma_f32_32x32x16_bf16(kA1, qf1, s, 0, 0, 0);
    bf16x8 kB0 = LDK(1, 0), kB1 = LDK(1, 1);
    bf16x8 pA0, pA1;
    EXPPACK(s, pA0, pA1);

    // invariant at head: pA=P(2j), vA=V(2j), kB=K(2j+1)
    for (int j = 0; j < 15; ++j) {
        const int t = 2 * j;
        // ---- even half: PV(t) + dn(t), QK(t+1) ----
        bf16x8 vB0 = LDV(t + 1, 0), vB1 = LDV(t + 1, 1);
        bf16x8 nk0 = LDK(t + 2, 0), nk1 = LDK(t + 2, 1);
        __builtin_amdgcn_s_setprio(1);
        s  = __builtin_amdgcn_mfma_f32_32x32x16_bf16(kB0, qf0, zz, 0, 0, 0);
        s  = __builtin_amdgcn_mfma_f32_32x32x16_bf16(kB1, qf1, s, 0, 0, 0);
        ot = __builtin_amdgcn_mfma_f32_32x32x16_bf16(vA0, pA0, ot, 0, 0, 0);
        dn = __builtin_amdgcn_mfma_f32_32x32x16_bf16(ONES.v, pA0, dn, 0, 0, 0);
        ot = __builtin_amdgcn_mfma_f32_32x32x16_bf16(vA1, pA1, ot, 0, 0, 0);
        dn = __builtin_amdgcn_mfma_f32_32x32x16_bf16(ONES.v, pA1, dn, 0, 0, 0);
        __builtin_amdgcn_s_setprio(0);
        bf16x8 pB0, pB1;
        EXPPACK(s, pB0, pB1);

        // ---- odd half: PV(t+1) + dn(t+1), QK(t+2) ----
        vA0 = LDV(t + 2, 0); vA1 = LDV(t + 2, 1);
        kB0 = LDK(t + 3, 0); kB1 = LDK(t + 3, 1);
        __builtin_amdgcn_s_setprio(1);
        s  = __builtin_amdgcn_mfma_f32_32x32x16_bf16(nk0, qf0, zz, 0, 0, 0);
        s  = __builtin_amdgcn_mfma_f32_32x32x16_bf16(nk1, qf1, s, 0, 0, 0);
        ot = __builtin_amdgcn_mfma_f32_32x32x16_bf16(vB0, pB0, ot, 0, 0, 0);
        dn = __builtin_amdgcn_mfma_f32_32x32x16_bf16(ONES.v, pB0, dn, 0, 0, 0);
        ot = __builtin_amdgcn_mfma_f32_32x32x16_bf16(vB1, pB1, ot, 0, 0, 0);
        dn = __builtin_amdgcn_mfma_f32_32x32x16_bf16(ONES.v, pB1, dn, 0, 0, 0);
        __builtin_amdgcn_s_setprio(0);
        EXPPACK(s, pA0, pA1);
    }

    // ---- epilogue: tiles 30 (PV) and 31 (QK+PV) ----
    {
        bf16x8 vB0 = LDV(31, 0), vB1 = LDV(31, 1);
        __builtin_amdgcn_s_setprio(1);
        s  = __builtin_amdgcn_mfma_f32_32x32x16_bf16(kB0, qf0, zz, 0, 0, 0);
        s  = __builtin_amdgcn_mfma_f32_32x32x16_bf16(kB1, qf1, s, 0, 0, 0);
        ot = __builtin_amdgcn_mfma_f32_32x32x16_bf16(vA0, pA0, ot, 0, 0, 0);
        dn = __builtin_amdgcn_mfma_f32_32x32x16_bf16(ONES.v, pA0, dn, 0, 0, 0);
        ot = __builtin_amdgcn_mfma_f32_32x32x16_bf16(vA1, pA1, ot, 0, 0, 0);
        dn = __builtin_amdgcn_mfma_f32_32x32x16_bf16(ONES.v, pA1, dn, 0, 0, 0);
        __builtin_amdgcn_s_setprio(0);
        bf16x8 pB0, pB1;
        EXPPACK(s, pB0, pB1);
        __builtin_amdgcn_s_setprio(1);
        ot = __builtin_amdgcn_mfma_f32_32x32x16_bf16(vB0, pB0, ot, 0, 0, 0);
        dn = __builtin_amdgcn_mfma_f32_32x32x16_bf16(ONES.v, pB0, dn, 0, 0, 0);
        ot = __builtin_amdgcn_mfma_f32_32x32x16_bf16(vB1, pB1, ot, 0, 0, 0);
        dn = __builtin_amdgcn_mfma_f32_32x32x16_bf16(ONES.v, pB1, dn, 0, 0, 0);
        __builtin_amdgcn_s_setprio(0);
    }

    // dn[0] = full per-wave denominator partial for q=n (all rows identical)
    if (khalf) {   // deposit partials
        #pragma unroll
        for (int i = 0; i < 16; ++i) Ol[qhalf][lane][i] = ot[i];
        Dl[qhalf][lane] = dn[0];
    }
    __syncthreads();
    if (!khalf) {  // combine, normalize, store
        #pragma unroll
        for (int i = 0; i < 16; ++i) ot[i] += Ol[qhalf][lane][i];
        const float dnt = dn[0] + Dl[qhalf][lane];
        const float inv = 1.0f / dnt;

        // O^T: col=q=n, row d32 = (r&3) + 8*(r>>2) + 4*hf
        u16* orow = ao + ((size_t)b * NS + q0w + n) * ND + h * NHD + 4 * hf;
        #pragma unroll
        for (int g = 0; g < 4; ++g) {
            uint2 wv = make_uint2(pk2(ot[4 * g] * inv, ot[4 * g + 1] * inv),
                                  pk2(ot[4 * g + 2] * inv, ot[4 * g + 3] * inv));
            *reinterpret_cast<uint2*>(orow + 8 * g) = wv;
        }
    }
}

// ============================================================
// Kernel 3: fused tail, HIGH-TLP: 16 rows/block, 4 col-split waves
// (wave cw = 16 rows x 32 cols, nb=2). Grid 2048 -> 8 blocks/CU.
// LN row-stats combined across the 4 col-waves via LDS.
// ============================================================
__global__ __launch_bounds__(256) void tail_kernel(
    const u16* __restrict__ A0, const u16* __restrict__ wto,
    const u16* __restrict__ wt1, const u16* __restrict__ wt2,
    const float* __restrict__ bo, const float* __restrict__ bf1,
    const float* __restrict__ bf2, const float* __restrict__ x,
    const float* __restrict__ g1, const float* __restrict__ b1,
    const float* __restrict__ g2, const float* __restrict__ b2,
    float* __restrict__ outp)
{
    __shared__ __align__(16) u16 tile[16][136];
    __shared__ float Sl[4][16];   // [cw][row] sum
    __shared__ float Sq[4][16];   // [cw][row] sumsq

    const int tid = threadIdx.x, lane = tid & 63, cw = tid >> 6;  // cw 0..3
    const int n = lane & 15, c = lane >> 4;
    const int row0 = blockIdx.x * 16;

    bf16x8 a[4];
    f32x4 acc[2];

    // residual x cached once (used by LN1 and LN2)
    float xres[2][4];
    #pragma unroll
    for (int nb = 0; nb < 2; ++nb) {
        const int col = cw * 32 + nb * 16 + n;
        #pragma unroll
        for (int r = 0; r < 4; ++r)
            xres[nb][r] = x[(size_t)(row0 + 4 * c + r) * ND + col];
    }

    // ---------- GEMM1: A0 @ Wo ----------
    #pragma unroll
    for (int kk = 0; kk < 4; ++kk)
        a[kk] = *reinterpret_cast<const bf16x8*>(
            A0 + (size_t)(row0 + n) * ND + kk * 32 + c * 8);
    #pragma unroll
    for (int nb = 0; nb < 2; ++nb) acc[nb] = f32x4{0.f, 0.f, 0.f, 0.f};
    #pragma unroll
    for (int kk = 0; kk < 4; ++kk)
        #pragma unroll
        for (int nb = 0; nb < 2; ++nb) {
            bf16x8 bw = *reinterpret_cast<const bf16x8*>(
                wto + (size_t)(cw * 32 + nb * 16 + n) * ND + kk * 32 + c * 8);
            acc[nb] = __builtin_amdgcn_mfma_f32_16x16x32_bf16(a[kk], bw, acc[nb], 0, 0, 0);
        }

    // ---------- LN1 (+bo +xres) -> tile ----------
    {
        float vals[2][4];
        float sr[4]  = {0.f, 0.f, 0.f, 0.f};
        float sr2[4] = {0.f, 0.f, 0.f, 0.f};
        #pragma unroll
        for (int nb = 0; nb < 2; ++nb) {
            const float bb = bo[cw * 32 + nb * 16 + n];
            #pragma unroll
            for (int r = 0; r < 4; ++r) {
                float vv = acc[nb][r] + bb + xres[nb][r];
                vals[nb][r] = vv;
                sr[r]  += vv;
                sr2[r] += vv * vv;
            }
        }
        #pragma unroll
        for (int m = 1; m < 16; m <<= 1)
            #pragma unroll
            for (int r = 0; r < 4; ++r) {
                sr[r]  += __shfl_xor(sr[r],  m);
                sr2[r] += __shfl_xor(sr2[r], m);
            }
        if (n == 0) {
            #pragma unroll
            for (int r = 0; r < 4; ++r) {
                Sl[cw][4 * c + r] = sr[r];
                Sq[cw][4 * c + r] = sr2[r];
            }
        }
        __syncthreads();
        #pragma unroll
        for (int r = 0; r < 4; ++r) {
            float st  = (Sl[0][4 * c + r] + Sl[1][4 * c + r])
                      + (Sl[2][4 * c + r] + Sl[3][4 * c + r]);
            float st2 = (Sq[0][4 * c + r] + Sq[1][4 * c + r])
                      + (Sq[2][4 * c + r] + Sq[3][4 * c + r]);
            float mean = st * (1.f / 128.f);
            float var  = fmaf(-mean, mean, st2 * (1.f / 128.f));
            float rstd = rsqrtf(var + 1e-5f);
            #pragma unroll
            for (int nb = 0; nb < 2; ++nb) {
                const int col = cw * 32 + nb * 16 + n;
                float y = fmaf((vals[nb][r] - mean) * rstd, g1[col], b1[col]);
                tile[4 * c + r][col] = f2bf(y);
            }
        }
    }
    __syncthreads();

    // ---------- GEMM2: attended @ W1, relu ----------
    #pragma unroll
    for (int kk = 0; kk < 4; ++kk)
        a[kk] = *reinterpret_cast<const bf16x8*>(&tile[n][kk * 32 + c * 8]);
    __syncthreads();   // all frag reads done before tile overwrite
    #pragma unroll
    for (int nb = 0; nb < 2; ++nb) acc[nb] = f32x4{0.f, 0.f, 0.f, 0.f};
    #pragma unroll
    for (int kk = 0; kk < 4; ++kk)
        #pragma unroll
        for (int nb = 0; nb < 2; ++nb) {
            bf16x8 bw = *reinterpret_cast<const bf16x8*>(
                wt1 + (size_t)(cw * 32 + nb * 16 + n) * ND + kk * 32 + c * 8);
            acc[nb] = __builtin_amdgcn_mfma_f32_16x16x32_bf16(a[kk], bw, acc[nb], 0, 0, 0);
        }
    #pragma unroll
    for (int nb = 0; nb < 2; ++nb) {
        const int col = cw * 32 + nb * 16 + n;
        const float bb = bf1[col];
        #pragma unroll
        for (int r = 0; r < 4; ++r)
            tile[4 * c + r][col] = f2bf(fmaxf(acc[nb][r] + bb, 0.f));
    }
    __syncthreads();

    // ---------- GEMM3: h @ W2, LN2 (+bf2 +xres) -> fp32 out ----------
    #pragma unroll
    for (int kk = 0; kk < 4; ++kk)
        a[kk] = *reinterpret_cast<const bf16x8*>(&tile[n][kk * 32 + c * 8]);
    #pragma unroll
    for (int nb = 0; nb < 2; ++nb) acc[nb] = f32x4{0.f, 0.f, 0.f, 0.f};
    #pragma unroll
    for (int kk = 0; kk < 4; ++kk)
        #pragma unroll
        for (int nb = 0; nb < 2; ++nb) {
            bf16x8 bw = *reinterpret_cast<const bf16x8*>(
                wt2 + (size_t)(cw * 32 + nb * 16 + n) * ND + kk * 32 + c * 8);
            acc[nb] = __builtin_amdgcn_mfma_f32_16x16x32_bf16(a[kk], bw, acc[nb], 0, 0, 0);
        }
    {
        float vals[2][4];
        float sr[4]  = {0.f, 0.f, 0.f, 0.f};
        float sr2[4] = {0.f, 0.f, 0.f, 0.f};
        #pragma unroll
        for (int nb = 0; nb < 2; ++nb) {
            const float bb = bf2[cw * 32 + nb * 16 + n];
            #pragma unroll
            for (int r = 0; r < 4; ++r) {
                float vv = acc[nb][r] + bb + xres[nb][r];
                vals[nb][r] = vv;
                sr[r]  += vv;
                sr2[r] += vv * vv;
            }
        }
        #pragma unroll
        for (int m = 1; m < 16; m <<= 1)
            #pragma unroll
            for (int r = 0; r < 4; ++r) {
                sr[r]  += __shfl_xor(sr[r],  m);
                sr2[r] += __shfl_xor(sr2[r], m);
            }
        __syncthreads();   // Sl/Sq from LN1 fully consumed (>=2 barriers back)
        if (n == 0) {
            #pragma unroll
            for (int r = 0; r < 4; ++r) {
                Sl[cw][4 * c + r] = sr[r];
                Sq[cw][4 * c + r] = sr2[r];
            }
        }
        __syncthreads();
        #pragma unroll
        for (int r = 0; r < 4; ++r) {
            float st  = (Sl[0][4 * c + r] + Sl[1][4 * c + r])
                      + (Sl[2][4 * c + r] + Sl[3][4 * c + r]);
            float st2 = (Sq[0][4 * c + r] + Sq[1][4 * c + r])
                      + (Sq[2][4 * c + r] + Sq[3][4 * c + r]);
            float mean = st * (1.f / 128.f);
            float var  = fmaf(-mean, mean, st2 * (1.f / 128.f));
            float rstd = rsqrtf(var + 1e-5f);
            #pragma unroll
            for (int nb = 0; nb < 2; ++nb) {
                const int col = cw * 32 + nb * 16 + n;
                float y = fmaf((vals[nb][r] - mean) * rstd, g2[col], b2[col]);
                outp[(size_t)(row0 + 4 * c + r) * ND + col] = y;
            }
        }
    }
}

// ============================================================
extern "C" void kernel_launch(void* const* d_in, const int* in_sizes, int n_in,
                              void* d_out, int out_size, void* d_ws, size_t ws_size,
                              hipStream_t stream)
{
    const float* x   = (const float*)d_in[0];
    const float* Wq  = (const float*)d_in[1];
    const float* bq  = (const float*)d_in[2];
    const float* Wk  = (const float*)d_in[3];
    const float* bk  = (const float*)d_in[4];
    const float* Wv  = (const float*)d_in[5];
    const float* bv  = (const float*)d_in[6];
    const float* Wo  = (const float*)d_in[7];
    const float* bo  = (const float*)d_in[8];
    const float* g1  = (const float*)d_in[9];
    const float* b1  = (const float*)d_in[10];
    const float* W1  = (const float*)d_in[11];
    const float* bf1 = (const float*)d_in[12];
    const float* W2  = (const float*)d_in[13];
    const float* bf2 = (const float*)d_in[14];
    const float* g2  = (const float*)d_in[15];
    const float* b2  = (const float*)d_in[16];
    float* outp = (float*)d_out;

    const size_t NE = (size_t)NROWS * ND;   // 4,194,304 elements
    u16* wt  = (u16*)d_ws;           // 6 transposed bf16 weights (6*16384)
    u16* qb  = wt + 6 * 16384;       // (B,H,S,32) row-major
    u16* kvb = qb + NE;              // interleaved frag-packed K|V (2*NE)
    u16* aob = kvb + 2 * NE;         // attn out bf16 (B,S,128)

    prep_kernel<<<dim3(48), dim3(256), 0, stream>>>(Wq, Wk, Wv, Wo, W1, W2, wt);
    qkv_mfma_kernel<<<dim3(NROWS / 16), dim3(256), 0, stream>>>(
        x, wt + 0 * 16384, wt + 1 * 16384, wt + 2 * 16384, bq, bk, bv, qb, kvb);
    attn_mfma_kernel<<<dim3(2048), dim3(256), 0, stream>>>(qb, kvb, aob);
    tail_kernel<<<dim3(NROWS / 16), dim3(256), 0, stream>>>(
        aob, wt + 3 * 16384, wt + 4 * 16384, wt + 5 * 16384,
        bo, bf1, bf2, x, g1, b1, g2, b2, outp);
}

// Round 14
// 127.457 us; speedup vs baseline: 1.0553x; 1.0553x over previous
//
#include <hip/hip_runtime.h>
#include <math.h>

#define NB   16
#define NS   2048
#define ND   128
#define NH   4
#define NHD  32
#define NROWS (NB * NS)   // 32768

typedef unsigned short u16;
typedef __bf16 bf16x8 __attribute__((ext_vector_type(8)));
typedef float  f32x4  __attribute__((ext_vector_type(4)));
typedef float  f32x16 __attribute__((ext_vector_type(16)));

static __device__ __forceinline__ u16 f2bf(float a) {
    union { __bf16 h; u16 u; } t; t.h = (__bf16)a; return t.u;
}
static __device__ __forceinline__ unsigned int pk2(float a, float b) {
    union { __bf16 h[2]; unsigned int u; } t;
    t.h[0] = (__bf16)a; t.h[1] = (__bf16)b; return t.u;
}

#if __has_builtin(__builtin_amdgcn_exp2f)
#define EXP2(x) __builtin_amdgcn_exp2f(x)
#else
extern "C" __device__ float __ocml_native_exp2_f32(float);
#define EXP2(x) __ocml_native_exp2_f32(x)
#endif

// q pre-scale: 1/sqrt(32) * log2(e)  -> softmax via raw v_exp_f32
#define QSCALE (0.17677669529663687f * 1.4426950408889634f)

// ============================================================
// Kernel 0: prep — 6 weights fp32 [k][n] -> bf16 transposed Wt[n][k].
// LDS transpose: coalesced float4 row-reads (was: stride-512B scalar
// gather on cold HBM), packed int4 transposed stores.
// 48 blocks: widx = wb/8 (matrix), sub = wb&7 (16-row slab).
// ============================================================
__global__ __launch_bounds__(256) void prep_kernel(
    const float* __restrict__ Wq, const float* __restrict__ Wk,
    const float* __restrict__ Wv, const float* __restrict__ Wo,
    const float* __restrict__ W1, const float* __restrict__ W2,
    u16* __restrict__ wt)
{
    __shared__ float ws[16][132];
    const int wb = blockIdx.x, tid = threadIdx.x;   // wb 0..47
    const int widx = wb >> 3, sub = wb & 7;
    const float* W = widx == 0 ? Wq : widx == 1 ? Wk : widx == 2 ? Wv
                   : widx == 3 ? Wo : widx == 4 ? W1 : W2;

    // load 16 rows (sub*16..+15) x 128 cols, coalesced float4
    #pragma unroll
    for (int i = 0; i < 2; ++i) {
        const int e  = tid + i * 256;   // float4 index 0..511
        const int r  = e >> 5;          // 32 float4 per row
        const int c4 = e & 31;
        float4 v = *reinterpret_cast<const float4*>(
            W + (size_t)(sub * 16 + r) * ND + c4 * 4);
        *reinterpret_cast<float4*>(&ws[r][c4 * 4]) = v;
    }
    __syncthreads();

    // write transposed: thread t -> out-col n = t>>1, k-octet kq = (t&1)*8
    const int n = tid >> 1, kq = (tid & 1) * 8;
    float v[8];
    #pragma unroll
    for (int j = 0; j < 8; ++j) v[j] = ws[kq + j][n];
    int4 o;
    o.x = pk2(v[0], v[1]); o.y = pk2(v[2], v[3]);
    o.z = pk2(v[4], v[5]); o.w = pk2(v[6], v[7]);
    *reinterpret_cast<int4*>(
        wt + (size_t)widx * 16384 + (size_t)n * ND + sub * 16 + kq) = o;
}

// ============================================================
// Kernel 1: fused QKV via MFMA, col-split waves (R10 verbatim — best
// measured residue). Block = 256 thr = 4 waves; wave (rw=w>>1, cw=w&1)
// owns rows rw*16..+15, cols cw*64..+63. Grid 1024.
// Outputs:
//   q  -> ROW-MAJOR (B,H,S,32) bf16 pre-scaled (LDS transpose, int4)
//   kv -> interleaved frag-packed per 32-key chunk (4KB = K|V)
// ============================================================
__global__ __launch_bounds__(256) void qkv_mfma_kernel(
    const float* __restrict__ x,
    const u16* __restrict__ wtq, const u16* __restrict__ wtk, const u16* __restrict__ wtv,
    const float* __restrict__ bq, const float* __restrict__ bk, const float* __restrict__ bv,
    u16* __restrict__ qo, u16* __restrict__ kvf)
{
    __shared__ __align__(16) u16 tileQ[32][136];
    __shared__ __align__(16) u16 tileK[32][136];

    const int tid = threadIdx.x, lane = tid & 63, w = tid >> 6;
    const int rw = w >> 1, cw = w & 1;
    const int n = lane & 15, c = lane >> 4;
    const int row0 = blockIdx.x * 32;
    const int grow = row0 + rw * 16;

    bf16x8 a[4];
    #pragma unroll
    for (int kk = 0; kk < 4; ++kk) {
        const float* xp = x + (size_t)(grow + n) * ND + kk * 32 + c * 8;
        float4 f0 = *reinterpret_cast<const float4*>(xp);
        float4 f1 = *reinterpret_cast<const float4*>(xp + 4);
        union { unsigned int u[4]; bf16x8 v; } t;
        t.u[0] = pk2(f0.x, f0.y); t.u[1] = pk2(f0.z, f0.w);
        t.u[2] = pk2(f1.x, f1.y); t.u[3] = pk2(f1.z, f1.w);
        a[kk] = t.v;
    }

    f32x4 accq[4], acck[4], accv[4];
    #pragma unroll
    for (int nb = 0; nb < 4; ++nb) {
        accq[nb] = f32x4{0.f, 0.f, 0.f, 0.f};
        acck[nb] = f32x4{0.f, 0.f, 0.f, 0.f};
        accv[nb] = f32x4{0.f, 0.f, 0.f, 0.f};
    }

    #pragma unroll
    for (int kk = 0; kk < 4; ++kk) {
        #pragma unroll
        for (int nb = 0; nb < 4; ++nb) {
            const size_t boff = (size_t)(cw * 64 + nb * 16 + n) * ND + kk * 32 + c * 8;
            bf16x8 bqf = *reinterpret_cast<const bf16x8*>(wtq + boff);
            bf16x8 bkf = *reinterpret_cast<const bf16x8*>(wtk + boff);
            bf16x8 bvf = *reinterpret_cast<const bf16x8*>(wtv + boff);
            accq[nb] = __builtin_amdgcn_mfma_f32_16x16x32_bf16(a[kk], bqf, accq[nb], 0, 0, 0);
            acck[nb] = __builtin_amdgcn_mfma_f32_16x16x32_bf16(a[kk], bkf, acck[nb], 0, 0, 0);
            accv[nb] = __builtin_amdgcn_mfma_f32_16x16x32_bf16(a[kk], bvf, accv[nb], 0, 0, 0);
        }
    }

    const int b    = row0 >> 11;
    const int sp0b = row0 & (NS - 1);             // block's first spos (32-aligned)
    const int sp0  = sp0b + rw * 16;              // wave's first spos (16-aligned)

    #pragma unroll
    for (int nb = 0; nb < 4; ++nb) {
        const int col = cw * 64 + nb * 16 + n, hh = col >> 5, d32 = col & 31;
        const float bqv = bq[col], bkv = bk[col], bvv = bv[col];

        // q, k -> LDS tiles (bias/scale applied)
        #pragma unroll
        for (int r = 0; r < 4; ++r) {
            tileQ[rw * 16 + 4 * c + r][col] = f2bf((accq[nb][r] + bqv) * QSCALE);
            tileK[rw * 16 + 4 * c + r][col] = f2bf(acck[nb][r] + bkv);
        }

        // v: interleaved frag-packed + key-permuted, uint2 direct
        const size_t kvb2 = ((size_t)b * NH + hh) * (2 * NS * NHD);
        const int u2    = sp0 >> 4;
        const int lanep = d32 + 32 * (c & 1);
        const int j0    = 4 * (c >> 1);
        float v0 = accv[nb][0] + bvv, v1 = accv[nb][1] + bvv;
        float v2 = accv[nb][2] + bvv, v3 = accv[nb][3] + bvv;
        *reinterpret_cast<uint2*>(
            kvf + kvb2 + (size_t)(u2 >> 1) * 2048 + 1024 + (u2 & 1) * 512
                + (size_t)lanep * 8 + j0) =
            make_uint2(pk2(v0, v1), pk2(v2, v3));
    }

    __syncthreads();   // tiles complete across col-halves

    // q, k: LDS -> global, int4 stores. 512 Q + 512 K segs, 2 per thread each.
    #pragma unroll
    for (int i = 0; i < 2; ++i) {
        const int flat = tid + i * 256;           // 0..511
        const int lk = flat >> 4, m16 = flat & 15;
        const int col0 = m16 * 8;
        const int hh = col0 >> 5, d32 = col0 & 31;
        const int s2 = d32 >> 4, c22 = (d32 >> 3) & 1;
        const int gk = sp0b + lk;
        const int T = gk >> 5, l5 = gk & 31;
        const size_t kvb  = ((size_t)b * NH + hh) * (NS * NHD);
        const size_t kvb2 = ((size_t)b * NH + hh) * (2 * NS * NHD);
        int4 qv = *reinterpret_cast<const int4*>(&tileQ[lk][col0]);
        *reinterpret_cast<int4*>(qo + kvb + (size_t)gk * NHD + d32) = qv;
        int4 kv = *reinterpret_cast<const int4*>(&tileK[lk][col0]);
        *reinterpret_cast<int4*>(
            kvf + kvb2 + (size_t)T * 2048 + s2 * 512 + (size_t)(l5 + 32 * c22) * 8) = kv;
    }
}

// ============================================================
// Kernel 2: MFMA flash attention — FROZEN at R12 (67.6us):
// R6 structure + dn via ones-MFMA + interleaved K|V stream.
// ============================================================
__global__ __launch_bounds__(256) void attn_mfma_kernel(
    const u16* __restrict__ qg,   // (B,H,S,32) row-major bf16, pre-scaled
    const u16* __restrict__ kvf,  // interleaved frag-packed K|V
    u16* __restrict__ ao)         // (B,S,128) bf16
{
    __shared__ float Ol[2][64][17];
    __shared__ float Dl[2][64];

    const int tid = threadIdx.x, lane = tid & 63, w = tid >> 6;
    const int qhalf = w >> 1, khalf = w & 1;

    // XCD swizzle: bid = qblk*64 + g*8 + xcd  ->  bh = xcd*8 + g
    const int bid  = blockIdx.x;
    const int bh   = (bid & 7) * 8 + ((bid >> 3) & 7);
    const int qblk = bid >> 6;                 // 0..31
    const int b = bh >> 2, h = bh & 3;
    const int n = lane & 31, hf = lane >> 5;
    const int q0w = qblk * 64 + qhalf * 32;

    const size_t qbase = (size_t)bh * (NS * NHD);
    const bf16x8 qf0 = *reinterpret_cast<const bf16x8*>(
        qg + qbase + (size_t)(q0w + n) * NHD + 8 * hf);
    const bf16x8 qf1 = *reinterpret_cast<const bf16x8*>(
        qg + qbase + (size_t)(q0w + n) * NHD + 16 + 8 * hf);

    union { unsigned int u[4]; bf16x8 v; } ONES;
    ONES.u[0] = 0x3F803F80u; ONES.u[1] = 0x3F803F80u;
    ONES.u[2] = 0x3F803F80u; ONES.u[3] = 0x3F803F80u;

    f32x16 ot, dn, zz;
    #pragma unroll
    for (int i = 0; i < 16; ++i) { ot[i] = 0.f; dn[i] = 0.f; zz[i] = 0.f; }

    // wave's key half: 32 interleaved 4KB chunks (K at +0/+512, V at +1024/+1536)
    const u16* kv = kvf + (size_t)bh * (2 * NS * NHD) + (size_t)lane * 8
                        + (size_t)khalf * 32 * 2048;

    auto LDK = [&](int t, int half) {
        return *reinterpret_cast<const bf16x8*>(kv + (size_t)t * 2048 + half * 512);
    };
    auto LDV = [&](int t, int half) {
        return *reinterpret_cast<const bf16x8*>(kv + (size_t)t * 2048 + 1024 + half * 512);
    };
    auto EXPPACK = [&](const f32x16& s, bf16x8& w0, bf16x8& w1) {
        union { unsigned int u[4]; bf16x8 v; } a0, a1;
        #pragma unroll
        for (int i = 0; i < 4; ++i)
            a0.u[i] = pk2(EXP2(s[2 * i]), EXP2(s[2 * i + 1]));
        #pragma unroll
        for (int i = 0; i < 4; ++i)
            a1.u[i] = pk2(EXP2(s[8 + 2 * i]), EXP2(s[9 + 2 * i]));
        w0 = a0.v; w1 = a1.v;
    };

    // ---- prologue: tile 0 ----
    bf16x8 kA0 = LDK(0, 0), kA1 = LDK(0, 1);
    bf16x8 vA0 = LDV(0, 0), vA1 = LDV(0, 1);
    f32x16 s;
    s = __builtin_amdgcn_mfma_f32_32x32x16_bf16(kA0, qf0, zz, 0, 0, 0);
    s = __builtin_amdgcn_mfma_f32_32x32x16_bf16(kA1, qf1, s, 0, 0, 0);
    bf16x8 kB0 = LDK(1, 0), kB1 = LDK(1, 1);
    bf16x8 pA0, pA1;
    EXPPACK(s, pA0, pA1);

    // invariant at head: pA=P(2j), vA=V(2j), kB=K(2j+1)
    for (int j = 0; j < 15; ++j) {
        const int t = 2 * j;
        // ---- even half: PV(t) + dn(t), QK(t+1) ----
        bf16x8 vB0 = LDV(t + 1, 0), vB1 = LDV(t + 1, 1);
        bf16x8 nk0 = LDK(t + 2, 0), nk1 = LDK(t + 2, 1);
        __builtin_amdgcn_s_setprio(1);
        s  = __builtin_amdgcn_mfma_f32_32x32x16_bf16(kB0, qf0, zz, 0, 0, 0);
        s  = __builtin_amdgcn_mfma_f32_32x32x16_bf16(kB1, qf1, s, 0, 0, 0);
        ot = __builtin_amdgcn_mfma_f32_32x32x16_bf16(vA0, pA0, ot, 0, 0, 0);
        dn = __builtin_amdgcn_mfma_f32_32x32x16_bf16(ONES.v, pA0, dn, 0, 0, 0);
        ot = __builtin_amdgcn_mfma_f32_32x32x16_bf16(vA1, pA1, ot, 0, 0, 0);
        dn = __builtin_amdgcn_mfma_f32_32x32x16_bf16(ONES.v, pA1, dn, 0, 0, 0);
        __builtin_amdgcn_s_setprio(0);
        bf16x8 pB0, pB1;
        EXPPACK(s, pB0, pB1);

        // ---- odd half: PV(t+1) + dn(t+1), QK(t+2) ----
        vA0 = LDV(t + 2, 0); vA1 = LDV(t + 2, 1);
        kB0 = LDK(t + 3, 0); kB1 = LDK(t + 3, 1);
        __builtin_amdgcn_s_setprio(1);
        s  = __builtin_amdgcn_mfma_f32_32x32x16_bf16(nk0, qf0, zz, 0, 0, 0);
        s  = __builtin_amdgcn_mfma_f32_32x32x16_bf16(nk1, qf1, s, 0, 0, 0);
        ot = __builtin_amdgcn_mfma_f32_32x32x16_bf16(vB0, pB0, ot, 0, 0, 0);
        dn = __builtin_amdgcn_mfma_f32_32x32x16_bf16(ONES.v, pB0, dn, 0, 0, 0);
        ot = __builtin_amdgcn_mfma_f32_32x32x16_bf16(vB1, pB1, ot, 0, 0, 0);
        dn = __builtin_amdgcn_mfma_f32_32x32x16_bf16(ONES.v, pB1, dn, 0, 0, 0);
        __builtin_amdgcn_s_setprio(0);
        EXPPACK(s, pA0, pA1);
    }

    // ---- epilogue: tiles 30 (PV) and 31 (QK+PV) ----
    {
        bf16x8 vB0 = LDV(31, 0), vB1 = LDV(31, 1);
        __builtin_amdgcn_s_setprio(1);
        s  = __builtin_amdgcn_mfma_f32_32x32x16_bf16(kB0, qf0, zz, 0, 0, 0);
        s  = __builtin_amdgcn_mfma_f32_32x32x16_bf16(kB1, qf1, s, 0, 0, 0);
        ot = __builtin_amdgcn_mfma_f32_32x32x16_bf16(vA0, pA0, ot, 0, 0, 0);
        dn = __builtin_amdgcn_mfma_f32_32x32x16_bf16(ONES.v, pA0, dn, 0, 0, 0);
        ot = __builtin_amdgcn_mfma_f32_32x32x16_bf16(vA1, pA1, ot, 0, 0, 0);
        dn = __builtin_amdgcn_mfma_f32_32x32x16_bf16(ONES.v, pA1, dn, 0, 0, 0);
        __builtin_amdgcn_s_setprio(0);
        bf16x8 pB0, pB1;
        EXPPACK(s, pB0, pB1);
        __builtin_amdgcn_s_setprio(1);
        ot = __builtin_amdgcn_mfma_f32_32x32x16_bf16(vB0, pB0, ot, 0, 0, 0);
        dn = __builtin_amdgcn_mfma_f32_32x32x16_bf16(ONES.v, pB0, dn, 0, 0, 0);
        ot = __builtin_amdgcn_mfma_f32_32x32x16_bf16(vB1, pB1, ot, 0, 0, 0);
        dn = __builtin_amdgcn_mfma_f32_32x32x16_bf16(ONES.v, pB1, dn, 0, 0, 0);
        __builtin_amdgcn_s_setprio(0);
    }

    // dn[0] = full per-wave denominator partial for q=n (all rows identical)
    if (khalf) {   // deposit partials
        #pragma unroll
        for (int i = 0; i < 16; ++i) Ol[qhalf][lane][i] = ot[i];
        Dl[qhalf][lane] = dn[0];
    }
    __syncthreads();
    if (!khalf) {  // combine, normalize, store
        #pragma unroll
        for (int i = 0; i < 16; ++i) ot[i] += Ol[qhalf][lane][i];
        const float dnt = dn[0] + Dl[qhalf][lane];
        const float inv = 1.0f / dnt;

        // O^T: col=q=n, row d32 = (r&3) + 8*(r>>2) + 4*hf
        u16* orow = ao + ((size_t)b * NS + q0w + n) * ND + h * NHD + 4 * hf;
        #pragma unroll
        for (int g = 0; g < 4; ++g) {
            uint2 wv = make_uint2(pk2(ot[4 * g] * inv, ot[4 * g + 1] * inv),
                                  pk2(ot[4 * g + 2] * inv, ot[4 * g + 3] * inv));
            *reinterpret_cast<uint2*>(orow + 8 * g) = wv;
        }
    }
}

// ============================================================
// Kernel 3: fused tail, col-split waves (R10 verbatim — best residue).
// Block = 256 thr = 4 waves; wave (rw,cw) = rows rw*16..+15, cols cw*64..+63.
// Grid 1024. LN row-stats combined across the wave pair via LDS.
// ============================================================
__global__ __launch_bounds__(256) void tail_kernel(
    const u16* __restrict__ A0, const u16* __restrict__ wto,
    const u16* __restrict__ wt1, const u16* __restrict__ wt2,
    const float* __restrict__ bo, const float* __restrict__ bf1,
    const float* __restrict__ bf2, const float* __restrict__ x,
    const float* __restrict__ g1, const float* __restrict__ b1,
    const float* __restrict__ g2, const float* __restrict__ b2,
    float* __restrict__ outp)
{
    __shared__ __align__(16) u16 tile[32][136];
    __shared__ float Sl[2][2][16];   // [rw][cw][row] sum
    __shared__ float Sq[2][2][16];   // [rw][cw][row] sumsq

    const int tid = threadIdx.x, lane = tid & 63, w = tid >> 6;
    const int rw = w >> 1, cw = w & 1;
    const int n = lane & 15, c = lane >> 4;
    const int row0 = blockIdx.x * 32;
    const int grow = row0 + rw * 16;
    const int lrow = rw * 16;

    bf16x8 a[4];
    f32x4 acc[4];

    // residual x cached once (used by LN1 and LN2)
    float xres[4][4];
    #pragma unroll
    for (int nb = 0; nb < 4; ++nb) {
        const int col = cw * 64 + nb * 16 + n;
        #pragma unroll
        for (int r = 0; r < 4; ++r)
            xres[nb][r] = x[(size_t)(grow + 4 * c + r) * ND + col];
    }

    // ---------- GEMM1: A0 @ Wo ----------
    #pragma unroll
    for (int kk = 0; kk < 4; ++kk)
        a[kk] = *reinterpret_cast<const bf16x8*>(
            A0 + (size_t)(grow + n) * ND + kk * 32 + c * 8);
    #pragma unroll
    for (int nb = 0; nb < 4; ++nb) acc[nb] = f32x4{0.f, 0.f, 0.f, 0.f};
    #pragma unroll
    for (int kk = 0; kk < 4; ++kk)
        #pragma unroll
        for (int nb = 0; nb < 4; ++nb) {
            bf16x8 bw = *reinterpret_cast<const bf16x8*>(
                wto + (size_t)(cw * 64 + nb * 16 + n) * ND + kk * 32 + c * 8);
            acc[nb] = __builtin_amdgcn_mfma_f32_16x16x32_bf16(a[kk], bw, acc[nb], 0, 0, 0);
        }

    // ---------- LN1 (+bo +xres) -> tile ----------
    {
        float vals[4][4];
        float sr[4]  = {0.f, 0.f, 0.f, 0.f};
        float sr2[4] = {0.f, 0.f, 0.f, 0.f};
        #pragma unroll
        for (int nb = 0; nb < 4; ++nb) {
            const float bb = bo[cw * 64 + nb * 16 + n];
            #pragma unroll
            for (int r = 0; r < 4; ++r) {
                float vv = acc[nb][r] + bb + xres[nb][r];
                vals[nb][r] = vv;
                sr[r]  += vv;
                sr2[r] += vv * vv;
            }
        }
        #pragma unroll
        for (int m = 1; m < 16; m <<= 1)
            #pragma unroll
            for (int r = 0; r < 4; ++r) {
                sr[r]  += __shfl_xor(sr[r],  m);
                sr2[r] += __shfl_xor(sr2[r], m);
            }
        if (n == 0) {
            #pragma unroll
            for (int r = 0; r < 4; ++r) {
                Sl[rw][cw][4 * c + r] = sr[r];
                Sq[rw][cw][4 * c + r] = sr2[r];
            }
        }
        __syncthreads();
        #pragma unroll
        for (int r = 0; r < 4; ++r) {
            float st  = Sl[rw][0][4 * c + r] + Sl[rw][1][4 * c + r];
            float st2 = Sq[rw][0][4 * c + r] + Sq[rw][1][4 * c + r];
            float mean = st * (1.f / 128.f);
            float var  = fmaf(-mean, mean, st2 * (1.f / 128.f));
            float rstd = rsqrtf(var + 1e-5f);
            #pragma unroll
            for (int nb = 0; nb < 4; ++nb) {
                const int col = cw * 64 + nb * 16 + n;
                float y = fmaf((vals[nb][r] - mean) * rstd, g1[col], b1[col]);
                tile[lrow + 4 * c + r][col] = f2bf(y);
            }
        }
    }
    __syncthreads();

    // ---------- GEMM2: attended @ W1, relu ----------
    #pragma unroll
    for (int kk = 0; kk < 4; ++kk)
        a[kk] = *reinterpret_cast<const bf16x8*>(&tile[lrow + n][kk * 32 + c * 8]);
    __syncthreads();   // all frag reads done before tile overwrite
    #pragma unroll
    for (int nb = 0; nb < 4; ++nb) acc[nb] = f32x4{0.f, 0.f, 0.f, 0.f};
    #pragma unroll
    for (int kk = 0; kk < 4; ++kk)
        #pragma unroll
        for (int nb = 0; nb < 4; ++nb) {
            bf16x8 bw = *reinterpret_cast<const bf16x8*>(
                wt1 + (size_t)(cw * 64 + nb * 16 + n) * ND + kk * 32 + c * 8);
            acc[nb] = __builtin_amdgcn_mfma_f32_16x16x32_bf16(a[kk], bw, acc[nb], 0, 0, 0);
        }
    #pragma unroll
    for (int nb = 0; nb < 4; ++nb) {
        const int col = cw * 64 + nb * 16 + n;
        const float bb = bf1[col];
        #pragma unroll
        for (int r = 0; r < 4; ++r)
            tile[lrow + 4 * c + r][col] = f2bf(fmaxf(acc[nb][r] + bb, 0.f));
    }
    __syncthreads();

    // ---------- GEMM3: h @ W2, LN2 (+bf2 +xres) -> fp32 out ----------
    #pragma unroll
    for (int kk = 0; kk < 4; ++kk)
        a[kk] = *reinterpret_cast<const bf16x8*>(&tile[lrow + n][kk * 32 + c * 8]);
    #pragma unroll
    for (int nb = 0; nb < 4; ++nb) acc[nb] = f32x4{0.f, 0.f, 0.f, 0.f};
    #pragma unroll
    for (int kk = 0; kk < 4; ++kk)
        #pragma unroll
        for (int nb = 0; nb < 4; ++nb) {
            bf16x8 bw = *reinterpret_cast<const bf16x8*>(
                wt2 + (size_t)(cw * 64 + nb * 16 + n) * ND + kk * 32 + c * 8);
            acc[nb] = __builtin_amdgcn_mfma_f32_16x16x32_bf16(a[kk], bw, acc[nb], 0, 0, 0);
        }
    {
        float vals[4][4];
        float sr[4]  = {0.f, 0.f, 0.f, 0.f};
        float sr2[4] = {0.f, 0.f, 0.f, 0.f};
        #pragma unroll
        for (int nb = 0; nb < 4; ++nb) {
            const float bb = bf2[cw * 64 + nb * 16 + n];
            #pragma unroll
            for (int r = 0; r < 4; ++r) {
                float vv = acc[nb][r] + bb + xres[nb][r];
                vals[nb][r] = vv;
                sr[r]  += vv;
                sr2[r] += vv * vv;
            }
        }
        #pragma unroll
        for (int m = 1; m < 16; m <<= 1)
            #pragma unroll
            for (int r = 0; r < 4; ++r) {
                sr[r]  += __shfl_xor(sr[r],  m);
                sr2[r] += __shfl_xor(sr2[r], m);
            }
        __syncthreads();   // Sl/Sq from LN1 fully consumed
        if (n == 0) {
            #pragma unroll
            for (int r = 0; r < 4; ++r) {
                Sl[rw][cw][4 * c + r] = sr[r];
                Sq[rw][cw][4 * c + r] = sr2[r];
            }
        }
        __syncthreads();
        #pragma unroll
        for (int r = 0; r < 4; ++r) {
            float st  = Sl[rw][0][4 * c + r] + Sl[rw][1][4 * c + r];
            float st2 = Sq[rw][0][4 * c + r] + Sq[rw][1][4 * c + r];
            float mean = st * (1.f / 128.f);
            float var  = fmaf(-mean, mean, st2 * (1.f / 128.f));
            float rstd = rsqrtf(var + 1e-5f);
            #pragma unroll
            for (int nb = 0; nb < 4; ++nb) {
                const int col = cw * 64 + nb * 16 + n;
                float y = fmaf((vals[nb][r] - mean) * rstd, g2[col], b2[col]);
                outp[(size_t)(grow + 4 * c + r) * ND + col] = y;
            }
        }
    }
}

// ============================================================
extern "C" void kernel_launch(void* const* d_in, const int* in_sizes, int n_in,
                              void* d_out, int out_size, void* d_ws, size_t ws_size,
                              hipStream_t stream)
{
    const float* x   = (const float*)d_in[0];
    const float* Wq  = (const float*)d_in[1];
    const float* bq  = (const float*)d_in[2];
    const float* Wk  = (const float*)d_in[3];
    const float* bk  = (const float*)d_in[4];
    const float* Wv  = (const float*)d_in[5];
    const float* bv  = (const float*)d_in[6];
    const float* Wo  = (const float*)d_in[7];
    const float* bo  = (const float*)d_in[8];
    const float* g1  = (const float*)d_in[9];
    const float* b1  = (const float*)d_in[10];
    const float* W1  = (const float*)d_in[11];
    const float* bf1 = (const float*)d_in[12];
    const float* W2  = (const float*)d_in[13];
    const float* bf2 = (const float*)d_in[14];
    const float* g2  = (const float*)d_in[15];
    const float* b2  = (const float*)d_in[16];
    float* outp = (float*)d_out;

    const size_t NE = (size_t)NROWS * ND;   // 4,194,304 elements
    u16* wt  = (u16*)d_ws;           // 6 transposed bf16 weights (6*16384)
    u16* qb  = wt + 6 * 16384;       // (B,H,S,32) row-major
    u16* kvb = qb + NE;              // interleaved frag-packed K|V (2*NE)
    u16* aob = kvb + 2 * NE;         // attn out bf16 (B,S,128)

    prep_kernel<<<dim3(48), dim3(256), 0, stream>>>(Wq, Wk, Wv, Wo, W1, W2, wt);
    qkv_mfma_kernel<<<dim3(NROWS / 32), dim3(256), 0, stream>>>(
        x, wt + 0 * 16384, wt + 1 * 16384, wt + 2 * 16384, bq, bk, bv, qb, kvb);
    attn_mfma_kernel<<<dim3(2048), dim3(256), 0, stream>>>(qb, kvb, aob);
    tail_kernel<<<dim3(NROWS / 32), dim3(256), 0, stream>>>(
        aob, wt + 3 * 16384, wt + 4 * 16384, wt + 5 * 16384,
        bo, bf1, bf2, x, g1, b1, g2, b2, outp);
}